// Round 1
// baseline (501.488 us; speedup 1.0000x reference)
//
#include <hip/hip_runtime.h>

// ---------------------------------------------------------------------------
// SingleHeadQKV: X@{Wq,Wk,Wv} -> rope+silu -> decay-masked QK^T -> @V -> GN
// B=2, T=4096, C=1024, bf16 MFMA 16x16x32, fp32 accumulate.
// ws layout (bf16/short elems): Qb[8M] Kb[8M] Vb[8M] Ab[32M]  = 112 MB
// ---------------------------------------------------------------------------

typedef __attribute__((ext_vector_type(8))) short bf16x8;
typedef __attribute__((ext_vector_type(4))) short bf16x4;
typedef __attribute__((ext_vector_type(4))) float f32x4;

#define MFMA16(a, b, c) __builtin_amdgcn_mfma_f32_16x16x32_bf16(a, b, c, 0, 0, 0)

static __device__ __forceinline__ short f2bf(float f) {
  unsigned u = __builtin_bit_cast(unsigned, f);
  u = (u + 0x7fffu + ((u >> 16) & 1u)) >> 16;
  return (short)u;
}

#define T_LEN 4096
#define CIN 1024
#define NB_T 32  // 4096/128

// log2(0.99609375)
#define LOG2G (-0.0056465633f)
// log2(10000)/32
#define L2IF (0.41524101f)

// ---------------------------------------------------------------------------
// Kernel 1: QKV projection. grid (64 m-tiles, 24 n-tiles), block 256.
// n-tiles 0..7 -> Q, 8..15 -> K, 16..23 -> V. Epilogue: rope (Q,K cols<64)+silu.
// ---------------------------------------------------------------------------
__global__ __launch_bounds__(256, 2)
void qkv_kernel(const float* __restrict__ X, const float* __restrict__ Wq,
                const float* __restrict__ Wk, const float* __restrict__ Wv,
                short* __restrict__ Qb, short* __restrict__ Kb,
                short* __restrict__ Vb) {
  __shared__ __align__(16) short As[128][36];
  __shared__ __align__(16) short Bs[128][36];
  const int tid = threadIdx.x;
  const int lane = tid & 63;
  const int wave = tid >> 6;
  const int wm = wave >> 1, wn = wave & 1;
  const int l15 = lane & 15, quad = lane >> 4;
  const int m0 = blockIdx.x * 128;  // over 8192 rows (b*T+t)
  const int jn = blockIdx.y;        // 0..23
  const int mat = jn >> 3;          // 0=Q 1=K 2=V
  const int n0 = (jn & 7) * 128;    // 0..896
  const float* __restrict__ W = (mat == 0) ? Wq : (mat == 1) ? Wk : Wv;
  short* __restrict__ Ob = (mat == 0) ? Qb : (mat == 1) ? Kb : Vb;

  f32x4 acc[4][4];
#pragma unroll
  for (int i = 0; i < 4; ++i)
#pragma unroll
    for (int j = 0; j < 4; ++j) {
      f32x4 z = {0.f, 0.f, 0.f, 0.f};
      acc[i][j] = z;
    }

  const int arow = tid >> 3, ac = tid & 7;    // A staging
  const int bkk = tid >> 5, bnn = tid & 31;   // B staging (4x4 transpose)

  for (int k0 = 0; k0 < CIN; k0 += 32) {
    __syncthreads();
    // A tile: X[m0..+127][k0..+31] fp32 -> bf16, row-major
#pragma unroll
    for (int i = 0; i < 4; ++i) {
      int row = arow + 32 * i;
      float4 f = *(const float4*)&X[(size_t)(m0 + row) * CIN + k0 + ac * 4];
      bf16x4 v4 = {f2bf(f.x), f2bf(f.y), f2bf(f.z), f2bf(f.w)};
      *(bf16x4*)&As[row][ac * 4] = v4;
    }
    // B tile: W[k0..+31][n0..+127] -> Bs[n][k] (transpose + convert)
    {
      float4 fr0 = *(const float4*)&W[(size_t)(k0 + bkk * 4 + 0) * CIN + n0 + bnn * 4];
      float4 fr1 = *(const float4*)&W[(size_t)(k0 + bkk * 4 + 1) * CIN + n0 + bnn * 4];
      float4 fr2 = *(const float4*)&W[(size_t)(k0 + bkk * 4 + 2) * CIN + n0 + bnn * 4];
      float4 fr3 = *(const float4*)&W[(size_t)(k0 + bkk * 4 + 3) * CIN + n0 + bnn * 4];
#pragma unroll
      for (int j = 0; j < 4; ++j) {
        bf16x4 v4 = {f2bf(((const float*)&fr0)[j]), f2bf(((const float*)&fr1)[j]),
                     f2bf(((const float*)&fr2)[j]), f2bf(((const float*)&fr3)[j])};
        *(bf16x4*)&Bs[bnn * 4 + j][bkk * 4] = v4;
      }
    }
    __syncthreads();
    bf16x8 af[4], bfr[4];
#pragma unroll
    for (int im = 0; im < 4; ++im) {
      const short* p = &As[wm * 64 + im * 16 + l15][quad * 8];
      bf16x4 lo = *(const bf16x4*)p;
      bf16x4 hi = *(const bf16x4*)(p + 4);
      af[im] = __builtin_shufflevector(lo, hi, 0, 1, 2, 3, 4, 5, 6, 7);
    }
#pragma unroll
    for (int in = 0; in < 4; ++in) {
      const short* p = &Bs[wn * 64 + in * 16 + l15][quad * 8];
      bf16x4 lo = *(const bf16x4*)p;
      bf16x4 hi = *(const bf16x4*)(p + 4);
      bfr[in] = __builtin_shufflevector(lo, hi, 0, 1, 2, 3, 4, 5, 6, 7);
    }
#pragma unroll
    for (int im = 0; im < 4; ++im)
#pragma unroll
      for (int in = 0; in < 4; ++in)
        acc[im][in] = MFMA16(af[im], bfr[in], acc[im][in]);
  }

  // epilogue: rope (mat<2, col<64) then silu, store bf16
#pragma unroll
  for (int im = 0; im < 4; ++im) {
#pragma unroll
    for (int in = 0; in < 4; ++in) {
      const int colm = n0 + wn * 64 + in * 16 + l15;  // 0..1023
      const bool rope = (mat < 2) && (colm < 64);
      const float invf = exp2f(-L2IF * (float)(colm >> 1));
#pragma unroll
      for (int r = 0; r < 4; ++r) {
        float v = acc[im][in][r];
        int m = m0 + wm * 64 + im * 16 + quad * 4 + r;
        int t = m & (T_LEN - 1);
        float partner = __shfl_xor(v, 1, 64);
        if (rope) {
          float ang = (float)t * invf;
          float s_, c_;
          sincosf(ang, &s_, &c_);
          v = (colm & 1) ? (v * c_ + partner * s_) : (v * c_ - partner * s_);
        }
        v = v / (1.f + __expf(-v));  // silu
        Ob[(size_t)m * 1024 + colm] = f2bf(v);
      }
    }
  }
}

// ---------------------------------------------------------------------------
// Kernel 2: A' = decay o (Q K^T), bf16 out. grid (32 s-tiles, 32 t-tiles, 2 b).
// Blocks with si<ti are all-zero: just fill.
// ---------------------------------------------------------------------------
__global__ __launch_bounds__(256, 2)
void score_kernel(const short* __restrict__ Qb, const short* __restrict__ Kb,
                  short* __restrict__ Ab) {
  const int si = blockIdx.x, ti = blockIdx.y, b = blockIdx.z;
  const int tid = threadIdx.x;
  const int s0 = si * 128, t0 = ti * 128;

  if (si < ti) {  // entire tile below diagonal -> zeros
    uint4 z = make_uint4(0u, 0u, 0u, 0u);
#pragma unroll
    for (int i = 0; i < 8; ++i) {
      int id = tid + i * 256;  // 0..2047
      int row = id >> 4, c = id & 15;
      *(uint4*)&Ab[((size_t)(b * T_LEN + t0 + row)) * T_LEN + s0 + c * 8] = z;
    }
    return;
  }

  __shared__ __align__(16) short Qs[128][40];
  __shared__ __align__(16) short Ks[128][40];
  const int lane = tid & 63, wave = tid >> 6;
  const int wm = wave >> 1, wn = wave & 1;
  const int l15 = lane & 15, quad = lane >> 4;

  f32x4 acc[4][4];
#pragma unroll
  for (int i = 0; i < 4; ++i)
#pragma unroll
    for (int j = 0; j < 4; ++j) {
      f32x4 z = {0.f, 0.f, 0.f, 0.f};
      acc[i][j] = z;
    }

  const int srow = tid >> 2, sc = tid & 3;

  for (int k0 = 0; k0 < 1024; k0 += 32) {
    __syncthreads();
#pragma unroll
    for (int i = 0; i < 2; ++i) {
      int row = srow + 64 * i;
      uint4 q = *(const uint4*)&Qb[((size_t)(b * T_LEN + t0 + row)) * 1024 + k0 + sc * 8];
      *(uint4*)&Qs[row][sc * 8] = q;
      uint4 k = *(const uint4*)&Kb[((size_t)(b * T_LEN + s0 + row)) * 1024 + k0 + sc * 8];
      *(uint4*)&Ks[row][sc * 8] = k;
    }
    __syncthreads();
    bf16x8 af[4], bfr[4];
#pragma unroll
    for (int im = 0; im < 4; ++im)
      af[im] = *(const bf16x8*)&Qs[wm * 64 + im * 16 + l15][quad * 8];
#pragma unroll
    for (int in = 0; in < 4; ++in)
      bfr[in] = *(const bf16x8*)&Ks[wn * 64 + in * 16 + l15][quad * 8];
#pragma unroll
    for (int im = 0; im < 4; ++im)
#pragma unroll
      for (int in = 0; in < 4; ++in)
        acc[im][in] = MFMA16(af[im], bfr[in], acc[im][in]);
  }

#pragma unroll
  for (int im = 0; im < 4; ++im) {
#pragma unroll
    for (int in = 0; in < 4; ++in) {
      int s = s0 + wn * 64 + in * 16 + l15;
#pragma unroll
      for (int r = 0; r < 4; ++r) {
        int t = t0 + wm * 64 + im * 16 + quad * 4 + r;
        int d = s - t;
        float v = acc[im][in][r];
        v = (d < 0) ? 0.f : v * exp2f((float)d * LOG2G);
        Ab[((size_t)(b * T_LEN + t)) * T_LEN + s] = f2bf(v);
      }
    }
  }
}

// ---------------------------------------------------------------------------
// Kernel 3: out = A' V  (fp32 out). grid (8 d-tiles, 32 t-tiles, 2 b).
// k-loop (over s) starts at t0: everything before is zero by construction.
// ---------------------------------------------------------------------------
__global__ __launch_bounds__(256, 2)
void av_kernel(const short* __restrict__ Ab, const short* __restrict__ Vb,
               float* __restrict__ Out) {
  const int di = blockIdx.x, ti = blockIdx.y, b = blockIdx.z;
  const int tid = threadIdx.x;
  const int n0 = di * 128, t0 = ti * 128;

  __shared__ __align__(16) short As2[128][36];
  __shared__ __align__(16) short Vt[128][36];
  const int lane = tid & 63, wave = tid >> 6;
  const int wm = wave >> 1, wn = wave & 1;
  const int l15 = lane & 15, quad = lane >> 4;

  f32x4 acc[4][4];
#pragma unroll
  for (int i = 0; i < 4; ++i)
#pragma unroll
    for (int j = 0; j < 4; ++j) {
      f32x4 z = {0.f, 0.f, 0.f, 0.f};
      acc[i][j] = z;
    }

  const int srow = tid >> 2, sc = tid & 3;
  const int bkk = tid >> 5, bnn = tid & 31;

  for (int s = t0; s < T_LEN; s += 32) {
    __syncthreads();
    // A' tile (natural layout)
#pragma unroll
    for (int i = 0; i < 2; ++i) {
      int row = srow + 64 * i;
      uint4 a = *(const uint4*)&Ab[((size_t)(b * T_LEN + t0 + row)) * T_LEN + s + sc * 8];
      uint2 lo = make_uint2(a.x, a.y), hi = make_uint2(a.z, a.w);
      *(uint2*)&As2[row][sc * 8] = lo;
      *(uint2*)&As2[row][sc * 8 + 4] = hi;
    }
    // V tile transpose: Vt[n][k] = V[s+k][n0+n]
    {
      uint2 vr0 = *(const uint2*)&Vb[((size_t)(b * T_LEN + s + bkk * 4 + 0)) * 1024 + n0 + bnn * 4];
      uint2 vr1 = *(const uint2*)&Vb[((size_t)(b * T_LEN + s + bkk * 4 + 1)) * 1024 + n0 + bnn * 4];
      uint2 vr2 = *(const uint2*)&Vb[((size_t)(b * T_LEN + s + bkk * 4 + 2)) * 1024 + n0 + bnn * 4];
      uint2 vr3 = *(const uint2*)&Vb[((size_t)(b * T_LEN + s + bkk * 4 + 3)) * 1024 + n0 + bnn * 4];
#pragma unroll
      for (int j = 0; j < 4; ++j) {
        bf16x4 v4 = {((const short*)&vr0)[j], ((const short*)&vr1)[j],
                     ((const short*)&vr2)[j], ((const short*)&vr3)[j]};
        *(bf16x4*)&Vt[bnn * 4 + j][bkk * 4] = v4;
      }
    }
    __syncthreads();
    bf16x8 af[4], bfr[4];
#pragma unroll
    for (int im = 0; im < 4; ++im) {
      const short* p = &As2[wm * 64 + im * 16 + l15][quad * 8];
      bf16x4 lo = *(const bf16x4*)p;
      bf16x4 hi = *(const bf16x4*)(p + 4);
      af[im] = __builtin_shufflevector(lo, hi, 0, 1, 2, 3, 4, 5, 6, 7);
    }
#pragma unroll
    for (int in = 0; in < 4; ++in) {
      const short* p = &Vt[wn * 64 + in * 16 + l15][quad * 8];
      bf16x4 lo = *(const bf16x4*)p;
      bf16x4 hi = *(const bf16x4*)(p + 4);
      bfr[in] = __builtin_shufflevector(lo, hi, 0, 1, 2, 3, 4, 5, 6, 7);
    }
#pragma unroll
    for (int im = 0; im < 4; ++im)
#pragma unroll
      for (int in = 0; in < 4; ++in)
        acc[im][in] = MFMA16(af[im], bfr[in], acc[im][in]);
  }

#pragma unroll
  for (int im = 0; im < 4; ++im) {
#pragma unroll
    for (int in = 0; in < 4; ++in) {
      int n = n0 + wn * 64 + in * 16 + l15;
#pragma unroll
      for (int r = 0; r < 4; ++r) {
        int t = t0 + wm * 64 + im * 16 + quad * 4 + r;
        Out[((size_t)(b * T_LEN + t)) * 1024 + n] = acc[im][in][r];
      }
    }
  }
}

// ---------------------------------------------------------------------------
// Kernel 4: in-place GroupNorm (32 groups x 32 ch). one block per row.
// ---------------------------------------------------------------------------
__global__ __launch_bounds__(256)
void gn_kernel(float* __restrict__ Out, const float* __restrict__ gw,
               const float* __restrict__ gb) {
  const int row = blockIdx.x;
  const int tid = threadIdx.x;
  const int ch0 = tid * 4;
  float4 v = *(const float4*)&Out[(size_t)row * 1024 + ch0];
  float s = v.x + v.y + v.z + v.w;
  float q = v.x * v.x + v.y * v.y + v.z * v.z + v.w * v.w;
  s += __shfl_xor(s, 1, 64);
  q += __shfl_xor(q, 1, 64);
  s += __shfl_xor(s, 2, 64);
  q += __shfl_xor(q, 2, 64);
  s += __shfl_xor(s, 4, 64);
  q += __shfl_xor(q, 4, 64);
  float mean = s * (1.f / 32.f);
  float var = q * (1.f / 32.f) - mean * mean;
  float rstd = rsqrtf(var + 1e-6f);
  float4 o;
  o.x = (v.x - mean) * rstd * gw[ch0 + 0] + gb[ch0 + 0];
  o.y = (v.y - mean) * rstd * gw[ch0 + 1] + gb[ch0 + 1];
  o.z = (v.z - mean) * rstd * gw[ch0 + 2] + gb[ch0 + 2];
  o.w = (v.w - mean) * rstd * gw[ch0 + 3] + gb[ch0 + 3];
  *(float4*)&Out[(size_t)row * 1024 + ch0] = o;
}

// ---------------------------------------------------------------------------
extern "C" void kernel_launch(void* const* d_in, const int* in_sizes, int n_in,
                              void* d_out, int out_size, void* d_ws,
                              size_t ws_size, hipStream_t stream) {
  const float* X = (const float*)d_in[0];
  const float* Wq = (const float*)d_in[1];
  const float* Wk = (const float*)d_in[2];
  const float* Wv = (const float*)d_in[3];
  const float* gw = (const float*)d_in[4];
  const float* gb = (const float*)d_in[5];
  float* Out = (float*)d_out;

  short* Qb = (short*)d_ws;                       // 8M bf16
  short* Kb = Qb + (size_t)8192 * 1024;           // 8M
  short* Vb = Kb + (size_t)8192 * 1024;           // 8M
  short* Ab = Vb + (size_t)8192 * 1024;           // 32M (2*4096*4096)

  qkv_kernel<<<dim3(64, 24), 256, 0, stream>>>(X, Wq, Wk, Wv, Qb, Kb, Vb);
  score_kernel<<<dim3(32, 32, 2), 256, 0, stream>>>(Qb, Kb, Ab);
  av_kernel<<<dim3(8, 32, 2), 256, 0, stream>>>(Ab, Vb, Out);
  gn_kernel<<<8192, 256, 0, stream>>>(Out, gw, gb);
}

// Round 2
// 352.952 us; speedup vs baseline: 1.4208x; 1.4208x over previous
//
#include <hip/hip_runtime.h>

// ---------------------------------------------------------------------------
// SingleHeadQKV: X@{Wq,Wk,Wv} -> rope+silu -> decay-masked QK^T -> @V -> GN
// B=2, T=4096, C=1024. All GEMMs: m97-style 128x128 tile, BK=32,
// global_load_lds(16B) staging, bf16 MFMA 16x16x32, fp32 accumulate.
//
// ws layout (shorts):
//   Qb  [8192][1024]            @ 0        (16 MB)
//   Kb  [8192][1024]            @ 8M       (16 MB)
//   Vt  [1024][8192] transposed @ 16M      (16 MB)
//   Ab  [2*4096][4096]          @ 24M      (64 MB)   } aliased:
//   Xb  [8192][1024]            @ 24M      (16 MB)   } Xb/WT dead before
//   WT  [3072][1024]            @ 32M      ( 6 MB)   } score writes Ab
// total 112 MB
// ---------------------------------------------------------------------------

typedef __attribute__((ext_vector_type(8))) short bf16x8;
typedef __attribute__((ext_vector_type(4))) short bf16x4;
typedef __attribute__((ext_vector_type(4))) float f32x4;

#define MFMA16(a, b, c) __builtin_amdgcn_mfma_f32_16x16x32_bf16(a, b, c, 0, 0, 0)

static __device__ __forceinline__ short f2bf(float f) {
  unsigned u = __builtin_bit_cast(unsigned, f);
  u = (u + 0x7fffu + ((u >> 16) & 1u)) >> 16;
  return (short)u;
}

static __device__ __forceinline__ void gl_lds16(const void* g, void* l) {
  __builtin_amdgcn_global_load_lds(
      (const __attribute__((address_space(1))) void*)g,
      (__attribute__((address_space(3))) void*)l, 16, 0, 0);
}

#define T_LEN 4096
#define CIN 1024

// log2(0.99609375)
#define LOG2G (-0.0056465633f)
// log2(10000)/32
#define L2IF (0.41524101f)

// ---------------------------------------------------------------------------
// Kernel A: X fp32 -> bf16 row-major copy.
// ---------------------------------------------------------------------------
__global__ __launch_bounds__(256)
void convert_x(const float* __restrict__ X, short* __restrict__ Xb) {
  const size_t id = (size_t)blockIdx.x * 256 + threadIdx.x;
  float4 f = *(const float4*)&X[id * 4];
  bf16x4 v = {f2bf(f.x), f2bf(f.y), f2bf(f.z), f2bf(f.w)};
  *(bf16x4*)&Xb[id * 4] = v;
}

// ---------------------------------------------------------------------------
// Kernel B: WT[c][k] = W_mat[k][c%1024], bf16. 64x64 LDS tile transpose.
// grid (16 k-tiles, 16 n-tiles, 3 mats), block 256.
// ---------------------------------------------------------------------------
__global__ __launch_bounds__(256)
void transpose_w(const float* __restrict__ Wq, const float* __restrict__ Wk,
                 const float* __restrict__ Wv, short* __restrict__ WT) {
  const int k0 = blockIdx.x * 64, n0 = blockIdx.y * 64, mat = blockIdx.z;
  const float* __restrict__ W = (mat == 0) ? Wq : (mat == 1) ? Wk : Wv;
  __shared__ short tile[64][72];
  const int tid = threadIdx.x;
  const int r = tid >> 4, c = tid & 15;
#pragma unroll
  for (int i = 0; i < 4; ++i) {
    int row = r + 16 * i;
    float4 f = *(const float4*)&W[(size_t)(k0 + row) * CIN + n0 + c * 4];
    tile[c * 4 + 0][row] = f2bf(f.x);
    tile[c * 4 + 1][row] = f2bf(f.y);
    tile[c * 4 + 2][row] = f2bf(f.z);
    tile[c * 4 + 3][row] = f2bf(f.w);
  }
  __syncthreads();
  const int n = tid >> 2, seg = tid & 3;
  bf16x8 lo = *(const bf16x8*)&tile[n][seg * 16];
  bf16x8 hi = *(const bf16x8*)&tile[n][seg * 16 + 8];
  short* dst = &WT[(size_t)(mat * 1024 + n0 + n) * CIN + k0 + seg * 16];
  *(bf16x8*)dst = lo;
  *(bf16x8*)(dst + 8) = hi;
}

// ---------------------------------------------------------------------------
// Kernel C: QKV GEMM. C[m][c] = sum_k Xb[m][k] WT[c][k].  M=8192, N=3072.
// grid (64 m-tiles, 24 c-tiles). Epilogue: rope(Q,K cols<64) + silu.
// Q,K stored natural bf16; V stored transposed Vt[d][m].
// ---------------------------------------------------------------------------
__global__ __launch_bounds__(256, 2)
void qkv_gemm(const short* __restrict__ Xb, const short* __restrict__ WT,
              short* __restrict__ Qb, short* __restrict__ Kb,
              short* __restrict__ Vt) {
  __shared__ __align__(16) short As[128][32];
  __shared__ __align__(16) short Bs[128][32];
  const int tid = threadIdx.x;
  const int lane = tid & 63, wave = tid >> 6;
  const int wm = wave >> 1, wn = wave & 1;
  const int l15 = lane & 15, quad = lane >> 4;
  const int m0 = blockIdx.x * 128;
  const int c0 = blockIdx.y * 128;

  const int srow = wave * 16 + (lane >> 2);  // staging row within 0..63 block
  const int sk = (lane & 3) * 8;             // k offset (elems)

  f32x4 acc[4][4];
#pragma unroll
  for (int i = 0; i < 4; ++i)
#pragma unroll
    for (int j = 0; j < 4; ++j) {
      f32x4 z = {0.f, 0.f, 0.f, 0.f};
      acc[i][j] = z;
    }

  for (int k0 = 0; k0 < CIN; k0 += 32) {
    __syncthreads();
#pragma unroll
    for (int i = 0; i < 2; ++i) {
      int row = srow + i * 64;
      gl_lds16(&Xb[(size_t)(m0 + row) * CIN + k0 + sk], &As[row][sk]);
      gl_lds16(&WT[(size_t)(c0 + row) * CIN + k0 + sk], &Bs[row][sk]);
    }
    __syncthreads();
    bf16x8 af[4], bf[4];
#pragma unroll
    for (int im = 0; im < 4; ++im)
      af[im] = *(const bf16x8*)&As[wm * 64 + im * 16 + l15][quad * 8];
#pragma unroll
    for (int in = 0; in < 4; ++in)
      bf[in] = *(const bf16x8*)&Bs[wn * 64 + in * 16 + l15][quad * 8];
#pragma unroll
    for (int im = 0; im < 4; ++im)
#pragma unroll
      for (int in = 0; in < 4; ++in)
        acc[im][in] = MFMA16(af[im], bf[in], acc[im][in]);
  }

  const int mat = (c0 >> 10);  // block-uniform: 128 | 1024
#pragma unroll
  for (int im = 0; im < 4; ++im) {
#pragma unroll
    for (int in = 0; in < 4; ++in) {
      const int c = c0 + wn * 64 + in * 16 + l15;
      const int colm = c & 1023;
      const bool rope = (mat < 2) && (colm < 64);
      const float invf = exp2f(-L2IF * (float)(colm >> 1));
      const int mbase = m0 + wm * 64 + im * 16 + quad * 4;
      short vv[4];
#pragma unroll
      for (int r = 0; r < 4; ++r) {
        float v = acc[im][in][r];
        int m = mbase + r;
        int t = m & (T_LEN - 1);
        float partner = __shfl_xor(v, 1, 64);
        if (rope) {
          float ang = (float)t * invf;
          float s_, c_;
          sincosf(ang, &s_, &c_);
          v = (colm & 1) ? (v * c_ + partner * s_) : (v * c_ - partner * s_);
        }
        v = v / (1.f + __expf(-v));  // silu
        vv[r] = f2bf(v);
      }
      if (mat == 0) {
#pragma unroll
        for (int r = 0; r < 4; ++r) Qb[(size_t)(mbase + r) * 1024 + colm] = vv[r];
      } else if (mat == 1) {
#pragma unroll
        for (int r = 0; r < 4; ++r) Kb[(size_t)(mbase + r) * 1024 + colm] = vv[r];
      } else {
        bf16x4 v4 = {vv[0], vv[1], vv[2], vv[3]};
        *(bf16x4*)&Vt[(size_t)colm * 8192 + mbase] = v4;  // transposed
      }
    }
  }
}

// ---------------------------------------------------------------------------
// Kernel D: A' = decay o (Q K^T), bf16. grid (32 s-tiles, 32 t-tiles, 2 b).
// ---------------------------------------------------------------------------
__global__ __launch_bounds__(256, 2)
void score_kernel(const short* __restrict__ Qb, const short* __restrict__ Kb,
                  short* __restrict__ Ab) {
  const int si = blockIdx.x, ti = blockIdx.y, b = blockIdx.z;
  const int tid = threadIdx.x;
  const int s0 = si * 128, t0 = ti * 128;

  if (si < ti) {  // strictly below diagonal: zero fill
    uint4 z = make_uint4(0u, 0u, 0u, 0u);
#pragma unroll
    for (int i = 0; i < 8; ++i) {
      int id = tid + i * 256;
      int row = id >> 4, c = id & 15;
      *(uint4*)&Ab[((size_t)(b * T_LEN + t0 + row)) * T_LEN + s0 + c * 8] = z;
    }
    return;
  }

  __shared__ __align__(16) short Qs[128][32];
  __shared__ __align__(16) short Ks[128][32];
  const int lane = tid & 63, wave = tid >> 6;
  const int wm = wave >> 1, wn = wave & 1;
  const int l15 = lane & 15, quad = lane >> 4;
  const int srow = wave * 16 + (lane >> 2);
  const int sk = (lane & 3) * 8;

  f32x4 acc[4][4];
#pragma unroll
  for (int i = 0; i < 4; ++i)
#pragma unroll
    for (int j = 0; j < 4; ++j) {
      f32x4 z = {0.f, 0.f, 0.f, 0.f};
      acc[i][j] = z;
    }

  for (int k0 = 0; k0 < 1024; k0 += 32) {
    __syncthreads();
#pragma unroll
    for (int i = 0; i < 2; ++i) {
      int row = srow + i * 64;
      gl_lds16(&Qb[((size_t)(b * T_LEN + t0 + row)) * 1024 + k0 + sk], &Qs[row][sk]);
      gl_lds16(&Kb[((size_t)(b * T_LEN + s0 + row)) * 1024 + k0 + sk], &Ks[row][sk]);
    }
    __syncthreads();
    bf16x8 af[4], bf[4];
#pragma unroll
    for (int im = 0; im < 4; ++im)
      af[im] = *(const bf16x8*)&Qs[wm * 64 + im * 16 + l15][quad * 8];
#pragma unroll
    for (int in = 0; in < 4; ++in)
      bf[in] = *(const bf16x8*)&Ks[wn * 64 + in * 16 + l15][quad * 8];
#pragma unroll
    for (int im = 0; im < 4; ++im)
#pragma unroll
      for (int in = 0; in < 4; ++in)
        acc[im][in] = MFMA16(af[im], bf[in], acc[im][in]);
  }

#pragma unroll
  for (int im = 0; im < 4; ++im) {
#pragma unroll
    for (int in = 0; in < 4; ++in) {
      int s = s0 + wn * 64 + in * 16 + l15;
#pragma unroll
      for (int r = 0; r < 4; ++r) {
        int t = t0 + wm * 64 + im * 16 + quad * 4 + r;
        int d = s - t;
        float v = acc[im][in][r];
        v = (d < 0) ? 0.f : v * exp2f((float)d * LOG2G);
        Ab[((size_t)(b * T_LEN + t)) * T_LEN + s] = f2bf(v);
      }
    }
  }
}

// ---------------------------------------------------------------------------
// Kernel E: out = A' V  (fp32). grid (8 d-tiles, 32 t-tiles, 2 b).
// V comes pre-transposed as Vt[d][b*T+s]. s-loop starts at t0.
// ---------------------------------------------------------------------------
__global__ __launch_bounds__(256, 2)
void av_kernel(const short* __restrict__ Ab, const short* __restrict__ Vt,
               float* __restrict__ Out) {
  const int di = blockIdx.x, ti = blockIdx.y, b = blockIdx.z;
  const int tid = threadIdx.x;
  const int n0 = di * 128, t0 = ti * 128;

  __shared__ __align__(16) short As2[128][32];
  __shared__ __align__(16) short Vs[128][32];
  const int lane = tid & 63, wave = tid >> 6;
  const int wm = wave >> 1, wn = wave & 1;
  const int l15 = lane & 15, quad = lane >> 4;
  const int srow = wave * 16 + (lane >> 2);
  const int sk = (lane & 3) * 8;

  f32x4 acc[4][4];
#pragma unroll
  for (int i = 0; i < 4; ++i)
#pragma unroll
    for (int j = 0; j < 4; ++j) {
      f32x4 z = {0.f, 0.f, 0.f, 0.f};
      acc[i][j] = z;
    }

  for (int s = t0; s < T_LEN; s += 32) {
    __syncthreads();
#pragma unroll
    for (int i = 0; i < 2; ++i) {
      int row = srow + i * 64;
      gl_lds16(&Ab[((size_t)(b * T_LEN + t0 + row)) * T_LEN + s + sk], &As2[row][sk]);
      gl_lds16(&Vt[(size_t)(n0 + row) * 8192 + b * T_LEN + s + sk], &Vs[row][sk]);
    }
    __syncthreads();
    bf16x8 af[4], bf[4];
#pragma unroll
    for (int im = 0; im < 4; ++im)
      af[im] = *(const bf16x8*)&As2[wm * 64 + im * 16 + l15][quad * 8];
#pragma unroll
    for (int in = 0; in < 4; ++in)
      bf[in] = *(const bf16x8*)&Vs[wn * 64 + in * 16 + l15][quad * 8];
#pragma unroll
    for (int im = 0; im < 4; ++im)
#pragma unroll
      for (int in = 0; in < 4; ++in)
        acc[im][in] = MFMA16(af[im], bf[in], acc[im][in]);
  }

#pragma unroll
  for (int im = 0; im < 4; ++im) {
#pragma unroll
    for (int in = 0; in < 4; ++in) {
      int n = n0 + wn * 64 + in * 16 + l15;
#pragma unroll
      for (int r = 0; r < 4; ++r) {
        int t = t0 + wm * 64 + im * 16 + quad * 4 + r;
        Out[((size_t)(b * T_LEN + t)) * 1024 + n] = acc[im][in][r];
      }
    }
  }
}

// ---------------------------------------------------------------------------
// Kernel F: in-place GroupNorm (32 groups x 32 ch). one block per row.
// ---------------------------------------------------------------------------
__global__ __launch_bounds__(256)
void gn_kernel(float* __restrict__ Out, const float* __restrict__ gw,
               const float* __restrict__ gb) {
  const int row = blockIdx.x;
  const int tid = threadIdx.x;
  const int ch0 = tid * 4;
  float4 v = *(const float4*)&Out[(size_t)row * 1024 + ch0];
  float s = v.x + v.y + v.z + v.w;
  float q = v.x * v.x + v.y * v.y + v.z * v.z + v.w * v.w;
  s += __shfl_xor(s, 1, 64);
  q += __shfl_xor(q, 1, 64);
  s += __shfl_xor(s, 2, 64);
  q += __shfl_xor(q, 2, 64);
  s += __shfl_xor(s, 4, 64);
  q += __shfl_xor(q, 4, 64);
  float mean = s * (1.f / 32.f);
  float var = q * (1.f / 32.f) - mean * mean;
  float rstd = rsqrtf(var + 1e-6f);
  float4 o;
  o.x = (v.x - mean) * rstd * gw[ch0 + 0] + gb[ch0 + 0];
  o.y = (v.y - mean) * rstd * gw[ch0 + 1] + gb[ch0 + 1];
  o.z = (v.z - mean) * rstd * gw[ch0 + 2] + gb[ch0 + 2];
  o.w = (v.w - mean) * rstd * gw[ch0 + 3] + gb[ch0 + 3];
  *(float4*)&Out[(size_t)row * 1024 + ch0] = o;
}

// ---------------------------------------------------------------------------
extern "C" void kernel_launch(void* const* d_in, const int* in_sizes, int n_in,
                              void* d_out, int out_size, void* d_ws,
                              size_t ws_size, hipStream_t stream) {
  const float* X = (const float*)d_in[0];
  const float* Wq = (const float*)d_in[1];
  const float* Wk = (const float*)d_in[2];
  const float* Wv = (const float*)d_in[3];
  const float* gw = (const float*)d_in[4];
  const float* gb = (const float*)d_in[5];
  float* Out = (float*)d_out;

  short* Qb = (short*)d_ws;                        // 16 MB
  short* Kb = Qb + (size_t)8192 * 1024;            // 16 MB
  short* Vt = Kb + (size_t)8192 * 1024;            // 16 MB (transposed)
  short* Ab = Vt + (size_t)8192 * 1024;            // 64 MB
  short* Xb = Ab;                                  // aliases Ab (dead after qkv)
  short* WT = Xb + (size_t)8192 * 1024;            // 6 MB

  convert_x<<<8192, 256, 0, stream>>>(X, Xb);
  transpose_w<<<dim3(16, 16, 3), 256, 0, stream>>>(Wq, Wk, Wv, WT);
  qkv_gemm<<<dim3(64, 24), 256, 0, stream>>>(Xb, WT, Qb, Kb, Vt);
  score_kernel<<<dim3(32, 32, 2), 256, 0, stream>>>(Qb, Kb, Ab);
  av_kernel<<<dim3(8, 32, 2), 256, 0, stream>>>(Ab, Vt, Out);
  gn_kernel<<<8192, 256, 0, stream>>>(Out, gw, gb);
}

// Round 3
// 333.212 us; speedup vs baseline: 1.5050x; 1.0592x over previous
//
#include <hip/hip_runtime.h>

// ---------------------------------------------------------------------------
// SingleHeadQKV: X@{Wq,Wk,Wv} -> rope+silu -> decay-masked QK^T -> @V -> GN
// B=2, T=4096, C=1024. All GEMMs: m97-style 128x128 tile, BK=64,
// global_load_lds(16B) staging, bf16 MFMA 16x16x32, fp32 accumulate.
//
// ws layout (shorts):
//   Qb  [8192][1024]            @ 0        (16 MB)
//   Kb  [8192][1024]            @ 8M       (16 MB)
//   Vt  [1024][8192] transposed @ 16M      (16 MB)
//   Ab  [2*4096][4096]          @ 24M      (64 MB)   } aliased:
//   Xb  [8192][1024]            @ 24M      (16 MB)   } Xb/WT dead before
//   WT  [3072][1024]            @ 32M      ( 6 MB)   } score writes Ab
// total 112 MB.  Ab lower-triangle tiles (si<ti) are never written or read.
// ---------------------------------------------------------------------------

typedef __attribute__((ext_vector_type(8))) short bf16x8;
typedef __attribute__((ext_vector_type(4))) short bf16x4;
typedef __attribute__((ext_vector_type(4))) float f32x4;

#define MFMA16(a, b, c) __builtin_amdgcn_mfma_f32_16x16x32_bf16(a, b, c, 0, 0, 0)

static __device__ __forceinline__ short f2bf(float f) {
  unsigned u = __builtin_bit_cast(unsigned, f);
  u = (u + 0x7fffu + ((u >> 16) & 1u)) >> 16;
  return (short)u;
}

static __device__ __forceinline__ void gl_lds16(const void* g, void* l) {
  __builtin_amdgcn_global_load_lds(
      (const __attribute__((address_space(1))) void*)g,
      (__attribute__((address_space(3))) void*)l, 16, 0, 0);
}

#define T_LEN 4096
#define CIN 1024

// log2(0.99609375)
#define LOG2G (-0.0056465633f)
// log2(10000)/32
#define L2IF (0.41524101f)

// ---------------------------------------------------------------------------
// Kernel A: X fp32 -> bf16 row-major copy.
// ---------------------------------------------------------------------------
__global__ __launch_bounds__(256)
void convert_x(const float* __restrict__ X, short* __restrict__ Xb) {
  const size_t id = (size_t)blockIdx.x * 256 + threadIdx.x;
  float4 f = *(const float4*)&X[id * 4];
  bf16x4 v = {f2bf(f.x), f2bf(f.y), f2bf(f.z), f2bf(f.w)};
  *(bf16x4*)&Xb[id * 4] = v;
}

// ---------------------------------------------------------------------------
// Kernel B: WT[c][k] = W_mat[k][c%1024], bf16. 64x64 LDS tile transpose.
// ---------------------------------------------------------------------------
__global__ __launch_bounds__(256)
void transpose_w(const float* __restrict__ Wq, const float* __restrict__ Wk,
                 const float* __restrict__ Wv, short* __restrict__ WT) {
  const int k0 = blockIdx.x * 64, n0 = blockIdx.y * 64, mat = blockIdx.z;
  const float* __restrict__ W = (mat == 0) ? Wq : (mat == 1) ? Wk : Wv;
  __shared__ short tile[64][72];
  const int tid = threadIdx.x;
  const int r = tid >> 4, c = tid & 15;
#pragma unroll
  for (int i = 0; i < 4; ++i) {
    int row = r + 16 * i;
    float4 f = *(const float4*)&W[(size_t)(k0 + row) * CIN + n0 + c * 4];
    tile[c * 4 + 0][row] = f2bf(f.x);
    tile[c * 4 + 1][row] = f2bf(f.y);
    tile[c * 4 + 2][row] = f2bf(f.z);
    tile[c * 4 + 3][row] = f2bf(f.w);
  }
  __syncthreads();
  const int n = tid >> 2, seg = tid & 3;
  bf16x8 lo = *(const bf16x8*)&tile[n][seg * 16];
  bf16x8 hi = *(const bf16x8*)&tile[n][seg * 16 + 8];
  short* dst = &WT[(size_t)(mat * 1024 + n0 + n) * CIN + k0 + seg * 16];
  *(bf16x8*)dst = lo;
  *(bf16x8*)(dst + 8) = hi;
}

// ---------------------------------------------------------------------------
// Shared tile-GEMM machinery: BK=64, LDS [128][64] per operand.
// Staging: 4 rounds of gl_lds16; wave w, lane l covers rows i*32+w*8+(l>>3),
// col (l&7)*8 -> LDS dest = uniform base + lane*16 as required.
// ---------------------------------------------------------------------------
#define GEMM_DECLS()                                   \
  const int tid = threadIdx.x;                         \
  const int lane = tid & 63, wave = tid >> 6;          \
  const int wm = wave >> 1, wn = wave & 1;             \
  const int l15 = lane & 15, quad = lane >> 4;         \
  const int srow = wave * 8 + (lane >> 3);             \
  const int scol = (lane & 7) * 8;

#define ACC_INIT(acc)                                  \
  _Pragma("unroll") for (int i = 0; i < 4; ++i)        \
  _Pragma("unroll") for (int j = 0; j < 4; ++j) {      \
    f32x4 z = {0.f, 0.f, 0.f, 0.f};                    \
    acc[i][j] = z;                                     \
  }

#define STAGE_TILE(dst, src, ld, r0, k0)               \
  _Pragma("unroll") for (int i = 0; i < 4; ++i)        \
    gl_lds16(&src[(size_t)((r0) + i * 32 + srow) * (ld) + (k0) + scol], \
             &dst[i * 32 + srow][scol]);

#define FRAG_MFMA(As, Bs, acc)                                              \
  {                                                                         \
    bf16x8 af[4][2], bfr[4][2];                                             \
    _Pragma("unroll") for (int im = 0; im < 4; ++im)                        \
    _Pragma("unroll") for (int ks = 0; ks < 2; ++ks)                        \
      af[im][ks] = *(const bf16x8*)&As[wm * 64 + im * 16 + l15][ks * 32 + quad * 8]; \
    _Pragma("unroll") for (int in = 0; in < 4; ++in)                        \
    _Pragma("unroll") for (int ks = 0; ks < 2; ++ks)                        \
      bfr[in][ks] = *(const bf16x8*)&Bs[wn * 64 + in * 16 + l15][ks * 32 + quad * 8]; \
    _Pragma("unroll") for (int ks = 0; ks < 2; ++ks)                        \
    _Pragma("unroll") for (int im = 0; im < 4; ++im)                        \
    _Pragma("unroll") for (int in = 0; in < 4; ++in)                        \
      acc[im][in] = MFMA16(af[im][ks], bfr[in][ks], acc[im][in]);           \
  }

// ---------------------------------------------------------------------------
// Kernel C: QKV GEMM. C[m][c] = sum_k Xb[m][k] WT[c][k].  M=8192, N=3072.
// grid (64 m-tiles, 24 c-tiles). Epilogue: rope(Q,K cols<64) + silu.
// ---------------------------------------------------------------------------
__global__ __launch_bounds__(256, 2)
void qkv_gemm(const short* __restrict__ Xb, const short* __restrict__ WT,
              short* __restrict__ Qb, short* __restrict__ Kb,
              short* __restrict__ Vt) {
  __shared__ __align__(16) short As[128][64];
  __shared__ __align__(16) short Bs[128][64];
  GEMM_DECLS();
  const int m0 = blockIdx.x * 128;
  const int c0 = blockIdx.y * 128;

  f32x4 acc[4][4];
  ACC_INIT(acc);

  for (int k0 = 0; k0 < CIN; k0 += 64) {
    __syncthreads();
    STAGE_TILE(As, Xb, CIN, m0, k0);
    STAGE_TILE(Bs, WT, CIN, c0, k0);
    __syncthreads();
    FRAG_MFMA(As, Bs, acc);
  }

  const int mat = (c0 >> 10);  // block-uniform: 0=Q 1=K 2=V
#pragma unroll
  for (int im = 0; im < 4; ++im) {
#pragma unroll
    for (int in = 0; in < 4; ++in) {
      const int c = c0 + wn * 64 + in * 16 + l15;
      const int colm = c & 1023;
      const bool rope = (mat < 2) && (colm < 64);
      const float invf = exp2f(-L2IF * (float)(colm >> 1));
      const int mbase = m0 + wm * 64 + im * 16 + quad * 4;
      short vv[4];
#pragma unroll
      for (int r = 0; r < 4; ++r) {
        float v = acc[im][in][r];
        int m = mbase + r;
        int t = m & (T_LEN - 1);
        float partner = __shfl_xor(v, 1, 64);
        if (rope) {
          float ang = (float)t * invf;
          float s_, c_;
          sincosf(ang, &s_, &c_);
          v = (colm & 1) ? (v * c_ + partner * s_) : (v * c_ - partner * s_);
        }
        v = v / (1.f + __expf(-v));  // silu
        vv[r] = f2bf(v);
      }
      if (mat == 0) {
#pragma unroll
        for (int r = 0; r < 4; ++r) Qb[(size_t)(mbase + r) * 1024 + colm] = vv[r];
      } else if (mat == 1) {
#pragma unroll
        for (int r = 0; r < 4; ++r) Kb[(size_t)(mbase + r) * 1024 + colm] = vv[r];
      } else {
        bf16x4 v4 = {vv[0], vv[1], vv[2], vv[3]};
        *(bf16x4*)&Vt[(size_t)colm * 8192 + mbase] = v4;  // transposed
      }
    }
  }
}

// ---------------------------------------------------------------------------
// Kernel D: A' = decay o (Q K^T), bf16. Triangular grid: 528 tiles (si>=ti)
// per batch, grid (528, 2). Uniform work per block.
// ---------------------------------------------------------------------------
__global__ __launch_bounds__(256, 2)
void score_kernel(const short* __restrict__ Qb, const short* __restrict__ Kb,
                  short* __restrict__ Ab) {
  int idx = blockIdx.x;
  int ti = 0;
  while (idx >= 32 - ti) { idx -= 32 - ti; ++ti; }
  const int si = ti + idx;
  const int b = blockIdx.y;
  const int s0 = si * 128, t0 = ti * 128;

  __shared__ __align__(16) short Qs[128][64];
  __shared__ __align__(16) short Ks[128][64];
  GEMM_DECLS();

  f32x4 acc[4][4];
  ACC_INIT(acc);

  for (int k0 = 0; k0 < 1024; k0 += 64) {
    __syncthreads();
    STAGE_TILE(Qs, Qb, 1024, b * T_LEN + t0, k0);
    STAGE_TILE(Ks, Kb, 1024, b * T_LEN + s0, k0);
    __syncthreads();
    FRAG_MFMA(Qs, Ks, acc);
  }

#pragma unroll
  for (int im = 0; im < 4; ++im) {
#pragma unroll
    for (int in = 0; in < 4; ++in) {
      int s = s0 + wn * 64 + in * 16 + l15;
#pragma unroll
      for (int r = 0; r < 4; ++r) {
        int t = t0 + wm * 64 + im * 16 + quad * 4 + r;
        int d = s - t;
        float v = acc[im][in][r];
        v = (d < 0) ? 0.f : v * exp2f((float)d * LOG2G);
        Ab[((size_t)(b * T_LEN + t)) * T_LEN + s] = f2bf(v);
      }
    }
  }
}

// ---------------------------------------------------------------------------
// Kernel E: out = A' V  (fp32). Balanced pairing: block (p,b,di) handles
// t-tiles p and 31-p -> uniform 33 s-tiles (66 BK64 iters) per block.
// grid (16, 2, 8): di is slowest dim -> the 8 di-blocks sharing an A-stream
// have linear indices stride 32 (== 0 mod 8) -> same XCD -> L2-shared A.
// ---------------------------------------------------------------------------
__global__ __launch_bounds__(256, 2)
void av_kernel(const short* __restrict__ Ab, const short* __restrict__ Vt,
               float* __restrict__ Out) {
  const int p = blockIdx.x, b = blockIdx.y, di = blockIdx.z;
  const int n0 = di * 128;

  __shared__ __align__(16) short As2[128][64];
  __shared__ __align__(16) short Vs[128][64];
  GEMM_DECLS();

#pragma unroll 1
  for (int half = 0; half < 2; ++half) {
    const int ti = half ? (31 - p) : p;
    const int t0 = ti * 128;

    f32x4 acc[4][4];
    ACC_INIT(acc);

    for (int s = t0; s < T_LEN; s += 64) {
      __syncthreads();
      STAGE_TILE(As2, Ab, T_LEN, b * T_LEN + t0, s);
      STAGE_TILE(Vs, Vt, 8192, n0, b * T_LEN + s);
      __syncthreads();
      FRAG_MFMA(As2, Vs, acc);
    }

#pragma unroll
    for (int im = 0; im < 4; ++im) {
#pragma unroll
      for (int in = 0; in < 4; ++in) {
        int n = n0 + wn * 64 + in * 16 + l15;
#pragma unroll
        for (int r = 0; r < 4; ++r) {
          int t = t0 + wm * 64 + im * 16 + quad * 4 + r;
          Out[((size_t)(b * T_LEN + t)) * 1024 + n] = acc[im][in][r];
        }
      }
    }
  }
}

// ---------------------------------------------------------------------------
// Kernel F: in-place GroupNorm (32 groups x 32 ch). one block per row.
// ---------------------------------------------------------------------------
__global__ __launch_bounds__(256)
void gn_kernel(float* __restrict__ Out, const float* __restrict__ gw,
               const float* __restrict__ gb) {
  const int row = blockIdx.x;
  const int tid = threadIdx.x;
  const int ch0 = tid * 4;
  float4 v = *(const float4*)&Out[(size_t)row * 1024 + ch0];
  float s = v.x + v.y + v.z + v.w;
  float q = v.x * v.x + v.y * v.y + v.z * v.z + v.w * v.w;
  s += __shfl_xor(s, 1, 64);
  q += __shfl_xor(q, 1, 64);
  s += __shfl_xor(s, 2, 64);
  q += __shfl_xor(q, 2, 64);
  s += __shfl_xor(s, 4, 64);
  q += __shfl_xor(q, 4, 64);
  float mean = s * (1.f / 32.f);
  float var = q * (1.f / 32.f) - mean * mean;
  float rstd = rsqrtf(var + 1e-6f);
  float4 o;
  o.x = (v.x - mean) * rstd * gw[ch0 + 0] + gb[ch0 + 0];
  o.y = (v.y - mean) * rstd * gw[ch0 + 1] + gb[ch0 + 1];
  o.z = (v.z - mean) * rstd * gw[ch0 + 2] + gb[ch0 + 2];
  o.w = (v.w - mean) * rstd * gw[ch0 + 3] + gb[ch0 + 3];
  *(float4*)&Out[(size_t)row * 1024 + ch0] = o;
}

// ---------------------------------------------------------------------------
extern "C" void kernel_launch(void* const* d_in, const int* in_sizes, int n_in,
                              void* d_out, int out_size, void* d_ws,
                              size_t ws_size, hipStream_t stream) {
  const float* X = (const float*)d_in[0];
  const float* Wq = (const float*)d_in[1];
  const float* Wk = (const float*)d_in[2];
  const float* Wv = (const float*)d_in[3];
  const float* gw = (const float*)d_in[4];
  const float* gb = (const float*)d_in[5];
  float* Out = (float*)d_out;

  short* Qb = (short*)d_ws;                        // 16 MB
  short* Kb = Qb + (size_t)8192 * 1024;            // 16 MB
  short* Vt = Kb + (size_t)8192 * 1024;            // 16 MB (transposed)
  short* Ab = Vt + (size_t)8192 * 1024;            // 64 MB
  short* Xb = Ab;                                  // aliases Ab (dead after qkv)
  short* WT = Xb + (size_t)8192 * 1024;            // 6 MB

  convert_x<<<8192, 256, 0, stream>>>(X, Xb);
  transpose_w<<<dim3(16, 16, 3), 256, 0, stream>>>(Wq, Wk, Wv, WT);
  qkv_gemm<<<dim3(64, 24), 256, 0, stream>>>(Xb, WT, Qb, Kb, Vt);
  score_kernel<<<dim3(528, 2), 256, 0, stream>>>(Qb, Kb, Ab);
  av_kernel<<<dim3(16, 2, 8), 256, 0, stream>>>(Ab, Vt, Out);
  gn_kernel<<<8192, 256, 0, stream>>>(Out, gw, gb);
}

// Round 4
// 309.033 us; speedup vs baseline: 1.6228x; 1.0782x over previous
//
#include <hip/hip_runtime.h>

// ---------------------------------------------------------------------------
// SingleHeadQKV: X@{Wq,Wk,Wv} -> rope+silu -> decay-masked QK^T -> @V -> GN
// B=2, T=4096, C=1024. GEMMs: 128x128 (av: 64x128) tile, BK=64,
// global_load_lds(16B) staging, bf16 MFMA 16x16x32, fp32 accumulate.
//
// LDS chunk-XOR swizzle: logical 16B-chunk lc of row r is stored at physical
// chunk lc^(r&7). Staging keeps dest = uniform+lane*16 (gl_lds16 requirement)
// and permutes the GLOBAL source address per lane; fragment reads XOR the
// chunk index. Result: quad-group reads hit all 32 banks, 2 lanes/bank (free)
// instead of 16-way conflicts on a 128B-stride row.
//
// ws layout (shorts):
//   Qb  [8192][1024]            @ 0        (16 MB)
//   Kb  [8192][1024]            @ 8M       (16 MB)
//   Vt  [1024][8192] transposed @ 16M      (16 MB)
//   Ab  [2*4096][4096]          @ 24M      (64 MB)   } aliased:
//   Xb  [8192][1024]            @ 24M      (16 MB)   } Xb/WT dead before
//   WT  [3072][1024]            @ 32M      ( 6 MB)   } score writes Ab
// ---------------------------------------------------------------------------

typedef __attribute__((ext_vector_type(8))) short bf16x8;
typedef __attribute__((ext_vector_type(4))) short bf16x4;
typedef __attribute__((ext_vector_type(4))) float f32x4;

#define MFMA16(a, b, c) __builtin_amdgcn_mfma_f32_16x16x32_bf16(a, b, c, 0, 0, 0)

static __device__ __forceinline__ short f2bf(float f) {
  unsigned u = __builtin_bit_cast(unsigned, f);
  u = (u + 0x7fffu + ((u >> 16) & 1u)) >> 16;
  return (short)u;
}

static __device__ __forceinline__ void gl_lds16(const void* g, void* l) {
  __builtin_amdgcn_global_load_lds(
      (const __attribute__((address_space(1))) void*)g,
      (__attribute__((address_space(3))) void*)l, 16, 0, 0);
}

#define T_LEN 4096
#define CIN 1024

// log2(0.99609375)
#define LOG2G (-0.0056465633f)
// log2(10000)/32
#define L2IF (0.41524101f)

// ---------------------------------------------------------------------------
// Kernel A: X fp32 -> bf16 row-major copy.
// ---------------------------------------------------------------------------
__global__ __launch_bounds__(256)
void convert_x(const float* __restrict__ X, short* __restrict__ Xb) {
  const size_t id = (size_t)blockIdx.x * 256 + threadIdx.x;
  float4 f = *(const float4*)&X[id * 4];
  bf16x4 v = {f2bf(f.x), f2bf(f.y), f2bf(f.z), f2bf(f.w)};
  *(bf16x4*)&Xb[id * 4] = v;
}

// ---------------------------------------------------------------------------
// Kernel B: WT[c][k] = W_mat[k][c%1024], bf16. 64x64 LDS tile transpose.
// ---------------------------------------------------------------------------
__global__ __launch_bounds__(256)
void transpose_w(const float* __restrict__ Wq, const float* __restrict__ Wk,
                 const float* __restrict__ Wv, short* __restrict__ WT) {
  const int k0 = blockIdx.x * 64, n0 = blockIdx.y * 64, mat = blockIdx.z;
  const float* __restrict__ W = (mat == 0) ? Wq : (mat == 1) ? Wk : Wv;
  __shared__ short tile[64][72];
  const int tid = threadIdx.x;
  const int r = tid >> 4, c = tid & 15;
#pragma unroll
  for (int i = 0; i < 4; ++i) {
    int row = r + 16 * i;
    float4 f = *(const float4*)&W[(size_t)(k0 + row) * CIN + n0 + c * 4];
    tile[c * 4 + 0][row] = f2bf(f.x);
    tile[c * 4 + 1][row] = f2bf(f.y);
    tile[c * 4 + 2][row] = f2bf(f.z);
    tile[c * 4 + 3][row] = f2bf(f.w);
  }
  __syncthreads();
  const int n = tid >> 2, seg = tid & 3;
  bf16x8 lo = *(const bf16x8*)&tile[n][seg * 16];
  bf16x8 hi = *(const bf16x8*)&tile[n][seg * 16 + 8];
  short* dst = &WT[(size_t)(mat * 1024 + n0 + n) * CIN + k0 + seg * 16];
  *(bf16x8*)dst = lo;
  *(bf16x8*)(dst + 8) = hi;
}

// ---------------------------------------------------------------------------
// Shared tile-GEMM machinery: BK=64, LDS [rows][64] shorts, chunk-XOR swizzle.
// ---------------------------------------------------------------------------
#define GEMM_DECLS()                                   \
  const int tid = threadIdx.x;                         \
  const int lane = tid & 63, wave = tid >> 6;          \
  const int wm = wave >> 1, wn = wave & 1;             \
  const int l15 = lane & 15, quad = lane >> 4;         \
  const int srow = wave * 8 + (lane >> 3);             \
  const int scol = (lane & 7) * 8;                     \
  const int ssw = (((lane & 7) ^ (lane >> 3)) * 8);    \
  const int asw = (l15 & 7);

#define ACC_INIT4(acc)                                 \
  _Pragma("unroll") for (int i = 0; i < 4; ++i)        \
  _Pragma("unroll") for (int j = 0; j < 4; ++j) {      \
    f32x4 z = {0.f, 0.f, 0.f, 0.f};                    \
    acc[i][j] = z;                                     \
  }

// stages `nrows` (multiple of 32) rows of a BK=64 tile; global src is
// chunk-swizzled so that LDS physical layout == swizzled.
#define STAGE_TILE(dst, src, ld, r0, k0, nrows)        \
  _Pragma("unroll") for (int i = 0; i < (nrows) / 32; ++i) \
    gl_lds16(&src[(size_t)((r0) + i * 32 + srow) * (ld) + (k0) + ssw], \
             &dst[i * 32 + srow][scol]);

#define FRAG_MFMA44(As, Bs, acc)                                            \
  {                                                                         \
    bf16x8 af[4][2], bfr[4][2];                                             \
    _Pragma("unroll") for (int im = 0; im < 4; ++im)                        \
    _Pragma("unroll") for (int ks = 0; ks < 2; ++ks)                        \
      af[im][ks] = *(const bf16x8*)&As[wm * 64 + im * 16 + l15]             \
                       [((ks * 4 + quad) ^ asw) * 8];                       \
    _Pragma("unroll") for (int in = 0; in < 4; ++in)                        \
    _Pragma("unroll") for (int ks = 0; ks < 2; ++ks)                        \
      bfr[in][ks] = *(const bf16x8*)&Bs[wn * 64 + in * 16 + l15]            \
                        [((ks * 4 + quad) ^ asw) * 8];                      \
    _Pragma("unroll") for (int ks = 0; ks < 2; ++ks)                        \
    _Pragma("unroll") for (int im = 0; im < 4; ++im)                        \
    _Pragma("unroll") for (int in = 0; in < 4; ++in)                        \
      acc[im][in] = MFMA16(af[im][ks], bfr[in][ks], acc[im][in]);           \
  }

// ---------------------------------------------------------------------------
// Kernel C: QKV GEMM. C[m][c] = sum_k Xb[m][k] WT[c][k].  M=8192, N=3072.
// grid (64 m-tiles, 24 c-tiles). Epilogue: rope(Q,K cols<64) + silu.
// ---------------------------------------------------------------------------
__global__ __launch_bounds__(256, 2)
void qkv_gemm(const short* __restrict__ Xb, const short* __restrict__ WT,
              short* __restrict__ Qb, short* __restrict__ Kb,
              short* __restrict__ Vt) {
  __shared__ __align__(16) short As[128][64];
  __shared__ __align__(16) short Bs[128][64];
  GEMM_DECLS();
  const int m0 = blockIdx.x * 128;
  const int c0 = blockIdx.y * 128;

  f32x4 acc[4][4];
  ACC_INIT4(acc);

  for (int k0 = 0; k0 < CIN; k0 += 64) {
    __syncthreads();
    STAGE_TILE(As, Xb, CIN, m0, k0, 128);
    STAGE_TILE(Bs, WT, CIN, c0, k0, 128);
    __syncthreads();
    FRAG_MFMA44(As, Bs, acc);
  }

  const int mat = (c0 >> 10);  // block-uniform: 0=Q 1=K 2=V
#pragma unroll
  for (int im = 0; im < 4; ++im) {
#pragma unroll
    for (int in = 0; in < 4; ++in) {
      const int c = c0 + wn * 64 + in * 16 + l15;
      const int colm = c & 1023;
      const bool rope = (mat < 2) && (colm < 64);
      const float invf = exp2f(-L2IF * (float)(colm >> 1));
      const int mbase = m0 + wm * 64 + im * 16 + quad * 4;
      short vv[4];
#pragma unroll
      for (int r = 0; r < 4; ++r) {
        float v = acc[im][in][r];
        int m = mbase + r;
        int t = m & (T_LEN - 1);
        float partner = __shfl_xor(v, 1, 64);
        if (rope) {
          float ang = (float)t * invf;
          float s_, c_;
          sincosf(ang, &s_, &c_);
          v = (colm & 1) ? (v * c_ + partner * s_) : (v * c_ - partner * s_);
        }
        v = v / (1.f + __expf(-v));  // silu
        vv[r] = f2bf(v);
      }
      if (mat == 0) {
#pragma unroll
        for (int r = 0; r < 4; ++r) Qb[(size_t)(mbase + r) * 1024 + colm] = vv[r];
      } else if (mat == 1) {
#pragma unroll
        for (int r = 0; r < 4; ++r) Kb[(size_t)(mbase + r) * 1024 + colm] = vv[r];
      } else {
        bf16x4 v4 = {vv[0], vv[1], vv[2], vv[3]};
        *(bf16x4*)&Vt[(size_t)colm * 8192 + mbase] = v4;  // transposed
      }
    }
  }
}

// ---------------------------------------------------------------------------
// Kernel D: A' = decay o (Q K^T), bf16. Triangular grid: 528 tiles (si>=ti)
// per batch, grid (528, 2). Uniform work per block.
// ---------------------------------------------------------------------------
__global__ __launch_bounds__(256, 2)
void score_kernel(const short* __restrict__ Qb, const short* __restrict__ Kb,
                  short* __restrict__ Ab) {
  int idx = blockIdx.x;
  int ti = 0;
  while (idx >= 32 - ti) { idx -= 32 - ti; ++ti; }
  const int si = ti + idx;
  const int b = blockIdx.y;
  const int s0 = si * 128, t0 = ti * 128;

  __shared__ __align__(16) short Qs[128][64];
  __shared__ __align__(16) short Ks[128][64];
  GEMM_DECLS();

  f32x4 acc[4][4];
  ACC_INIT4(acc);

  for (int k0 = 0; k0 < 1024; k0 += 64) {
    __syncthreads();
    STAGE_TILE(Qs, Qb, 1024, b * T_LEN + t0, k0, 128);
    STAGE_TILE(Ks, Kb, 1024, b * T_LEN + s0, k0, 128);
    __syncthreads();
    FRAG_MFMA44(Qs, Ks, acc);
  }

#pragma unroll
  for (int im = 0; im < 4; ++im) {
#pragma unroll
    for (int in = 0; in < 4; ++in) {
      int s = s0 + wn * 64 + in * 16 + l15;
#pragma unroll
      for (int r = 0; r < 4; ++r) {
        int t = t0 + wm * 64 + im * 16 + quad * 4 + r;
        int d = s - t;
        float v = acc[im][in][r];
        v = (d < 0) ? 0.f : v * exp2f((float)d * LOG2G);
        Ab[((size_t)(b * T_LEN + t)) * T_LEN + s] = f2bf(v);
      }
    }
  }
}

// ---------------------------------------------------------------------------
// Kernel E: out = A' V (fp32). 64-row t-tiles, balanced pairing (p, 63-p):
// uniform 65 BK64-iters per block. grid (32, 2, 8) = 512 blocks, 24 KB LDS
// -> 2 blocks/CU. di slowest: A-stream-sharing blocks land on one XCD.
// ---------------------------------------------------------------------------
__global__ __launch_bounds__(256, 2)
void av_kernel(const short* __restrict__ Ab, const short* __restrict__ Vt,
               float* __restrict__ Out) {
  const int p = blockIdx.x, b = blockIdx.y, di = blockIdx.z;
  const int n0 = di * 128;

  __shared__ __align__(16) short As2[64][64];
  __shared__ __align__(16) short Vs[128][64];
  GEMM_DECLS();

#pragma unroll 1
  for (int half = 0; half < 2; ++half) {
    const int ti2 = half ? (63 - p) : p;  // 64-row tile index
    const int t0 = ti2 * 64;

    f32x4 acc[2][4];
#pragma unroll
    for (int i = 0; i < 2; ++i)
#pragma unroll
      for (int j = 0; j < 4; ++j) {
        f32x4 z = {0.f, 0.f, 0.f, 0.f};
        acc[i][j] = z;
      }

    for (int s = t0; s < T_LEN; s += 64) {
      __syncthreads();
      STAGE_TILE(As2, Ab, T_LEN, b * T_LEN + t0, s, 64);
      STAGE_TILE(Vs, Vt, 8192, n0, b * T_LEN + s, 128);
      __syncthreads();
      bf16x8 af[2][2], bfr[4][2];
#pragma unroll
      for (int im = 0; im < 2; ++im)
#pragma unroll
        for (int ks = 0; ks < 2; ++ks)
          af[im][ks] = *(const bf16x8*)&As2[wm * 32 + im * 16 + l15]
                           [((ks * 4 + quad) ^ asw) * 8];
#pragma unroll
      for (int in = 0; in < 4; ++in)
#pragma unroll
        for (int ks = 0; ks < 2; ++ks)
          bfr[in][ks] = *(const bf16x8*)&Vs[wn * 64 + in * 16 + l15]
                            [((ks * 4 + quad) ^ asw) * 8];
#pragma unroll
      for (int ks = 0; ks < 2; ++ks)
#pragma unroll
        for (int im = 0; im < 2; ++im)
#pragma unroll
          for (int in = 0; in < 4; ++in)
            acc[im][in] = MFMA16(af[im][ks], bfr[in][ks], acc[im][in]);
    }

#pragma unroll
    for (int im = 0; im < 2; ++im) {
#pragma unroll
      for (int in = 0; in < 4; ++in) {
        int n = n0 + wn * 64 + in * 16 + l15;
#pragma unroll
        for (int r = 0; r < 4; ++r) {
          int t = t0 + wm * 32 + im * 16 + quad * 4 + r;
          Out[((size_t)(b * T_LEN + t)) * 1024 + n] = acc[im][in][r];
        }
      }
    }
  }
}

// ---------------------------------------------------------------------------
// Kernel F: in-place GroupNorm (32 groups x 32 ch). one block per row.
// ---------------------------------------------------------------------------
__global__ __launch_bounds__(256)
void gn_kernel(float* __restrict__ Out, const float* __restrict__ gw,
               const float* __restrict__ gb) {
  const int row = blockIdx.x;
  const int tid = threadIdx.x;
  const int ch0 = tid * 4;
  float4 v = *(const float4*)&Out[(size_t)row * 1024 + ch0];
  float s = v.x + v.y + v.z + v.w;
  float q = v.x * v.x + v.y * v.y + v.z * v.z + v.w * v.w;
  s += __shfl_xor(s, 1, 64);
  q += __shfl_xor(q, 1, 64);
  s += __shfl_xor(s, 2, 64);
  q += __shfl_xor(q, 2, 64);
  s += __shfl_xor(s, 4, 64);
  q += __shfl_xor(q, 4, 64);
  float mean = s * (1.f / 32.f);
  float var = q * (1.f / 32.f) - mean * mean;
  float rstd = rsqrtf(var + 1e-6f);
  float4 o;
  o.x = (v.x - mean) * rstd * gw[ch0 + 0] + gb[ch0 + 0];
  o.y = (v.y - mean) * rstd * gw[ch0 + 1] + gb[ch0 + 1];
  o.z = (v.z - mean) * rstd * gw[ch0 + 2] + gb[ch0 + 2];
  o.w = (v.w - mean) * rstd * gw[ch0 + 3] + gb[ch0 + 3];
  *(float4*)&Out[(size_t)row * 1024 + ch0] = o;
}

// ---------------------------------------------------------------------------
extern "C" void kernel_launch(void* const* d_in, const int* in_sizes, int n_in,
                              void* d_out, int out_size, void* d_ws,
                              size_t ws_size, hipStream_t stream) {
  const float* X = (const float*)d_in[0];
  const float* Wq = (const float*)d_in[1];
  const float* Wk = (const float*)d_in[2];
  const float* Wv = (const float*)d_in[3];
  const float* gw = (const float*)d_in[4];
  const float* gb = (const float*)d_in[5];
  float* Out = (float*)d_out;

  short* Qb = (short*)d_ws;                        // 16 MB
  short* Kb = Qb + (size_t)8192 * 1024;            // 16 MB
  short* Vt = Kb + (size_t)8192 * 1024;            // 16 MB (transposed)
  short* Ab = Vt + (size_t)8192 * 1024;            // 64 MB
  short* Xb = Ab;                                  // aliases Ab (dead after qkv)
  short* WT = Xb + (size_t)8192 * 1024;            // 6 MB

  convert_x<<<8192, 256, 0, stream>>>(X, Xb);
  transpose_w<<<dim3(16, 16, 3), 256, 0, stream>>>(Wq, Wk, Wv, WT);
  qkv_gemm<<<dim3(64, 24), 256, 0, stream>>>(Xb, WT, Qb, Kb, Vt);
  score_kernel<<<dim3(528, 2), 256, 0, stream>>>(Qb, Kb, Ab);
  av_kernel<<<dim3(32, 2, 8), 256, 0, stream>>>(Ab, Vt, Out);
  gn_kernel<<<8192, 256, 0, stream>>>(Out, gw, gb);
}